// Round 5
// baseline (345.937 us; speedup 1.0000x reference)
//
#include <hip/hip_runtime.h>

#define L_LM 2000
#define F_DIM 64
#define B_SZ 2048

typedef float f32x4 __attribute__((ext_vector_type(4)));

// ---------------- Kernel 1: BMU (argmin of squared distance) ----------------
__global__ __launch_bounds__(256) void som_bmu_kernel(
    const float* __restrict__ x, const float* __restrict__ lm,
    int* __restrict__ min_idx)
{
    constexpr int ROWS = 8;
    const int b0 = blockIdx.x * ROWS;
    const int tid = threadIdx.x;

    __shared__ float xs[ROWS][F_DIM];
    for (int i = tid; i < ROWS * F_DIM; i += 256) {
        xs[i / F_DIM][i % F_DIM] = x[(size_t)(b0 + i / F_DIM) * F_DIM + (i % F_DIM)];
    }
    __syncthreads();

    float best[ROWS];
    int   bidx[ROWS];
#pragma unroll
    for (int r = 0; r < ROWS; ++r) { best[r] = 3.4e38f; bidx[r] = 0; }

    for (int l = tid; l < L_LM; l += 256) {
        const float4* lp = reinterpret_cast<const float4*>(lm + (size_t)l * F_DIM);
        float dot[ROWS];
        float l2 = 0.f;
#pragma unroll
        for (int r = 0; r < ROWS; ++r) dot[r] = 0.f;
#pragma unroll
        for (int k = 0; k < F_DIM / 4; ++k) {
            float4 v = lp[k];
            l2 += v.x * v.x + v.y * v.y + v.z * v.z + v.w * v.w;
#pragma unroll
            for (int r = 0; r < ROWS; ++r) {
                dot[r] += v.x * xs[r][4 * k + 0] + v.y * xs[r][4 * k + 1]
                        + v.z * xs[r][4 * k + 2] + v.w * xs[r][4 * k + 3];
            }
        }
#pragma unroll
        for (int r = 0; r < ROWS; ++r) {
            float s = l2 - 2.f * dot[r];
            if (s < best[r]) { best[r] = s; bidx[r] = l; }  // per-thread l ascending
        }
    }

    // Wave-level reduce (64 lanes), lexicographic (score, index)
#pragma unroll
    for (int r = 0; r < ROWS; ++r) {
        float s = best[r]; int i = bidx[r];
        for (int off = 32; off > 0; off >>= 1) {
            float s2 = __shfl_down(s, off);
            int   i2 = __shfl_down(i, off);
            if (s2 < s || (s2 == s && i2 < i)) { s = s2; i = i2; }
        }
        best[r] = s; bidx[r] = i;
    }

    __shared__ float sbest[4][ROWS];
    __shared__ int   sidx[4][ROWS];
    const int wave = tid >> 6;
    const int lane = tid & 63;
    if (lane == 0) {
#pragma unroll
        for (int r = 0; r < ROWS; ++r) { sbest[wave][r] = best[r]; sidx[wave][r] = bidx[r]; }
    }
    __syncthreads();
    if (tid < ROWS) {
        float s = sbest[0][tid]; int i = sidx[0][tid];
#pragma unroll
        for (int w = 1; w < 4; ++w) {
            float s2 = sbest[w][tid]; int i2 = sidx[w][tid];
            if (s2 < s || (s2 == s && i2 < i)) { s = s2; i = i2; }
        }
        min_idx[b0 + tid] = i;
    }
}

// ---------------- Kernel 2: delta0 write — fill-pattern grid-stride --------
// Theory: prior variants' instantaneous write footprint was scattered 4KB
// chunks / hundreds of interleaved 512KB-strided streams -> DRAM row-buffer
// thrash caps stores at ~4.3 TB/s. The 6.8 TB/s rocclr fill is a grid-stride
// linear sweep: all resident waves write one compact ~8MB window that slides.
// This kernel clones that pattern exactly: linear float4 index g4, stride =
// grid*256, plain stores. Inputs decoded from g4; all reads L1/L2-hot
// (window spans ~16 b-rows; lm is 512KB, qd rows 8KB, x rows 256B).
__global__ __launch_bounds__(256) void som_delta_kernel(
    const float* __restrict__ x, const float* __restrict__ lm,
    const float* __restrict__ qd, const int* __restrict__ min_idx,
    f32x4* __restrict__ out)
{
    constexpr unsigned N4    = (unsigned)B_SZ * L_LM * (F_DIM / 4);  // 65,536,000
    constexpr unsigned ROW4  = L_LM * (F_DIM / 4);                    // 32,000
    const unsigned stride = gridDim.x * 256u;
    const f32x4* __restrict__ lmv = reinterpret_cast<const f32x4*>(lm);
    const f32x4* __restrict__ xv4 = reinterpret_cast<const f32x4*>(x);

#pragma unroll 2
    for (unsigned g4 = blockIdx.x * 256u + threadIdx.x; g4 < N4; g4 += stride) {
        const unsigned b   = g4 / ROW4;            // magic-mul, const divisor
        const unsigned rem = g4 - b * ROW4;        // l*16 + f4
        const unsigned bmu = (unsigned)min_idx[b];
        const float h  = qd[bmu * (unsigned)L_LM + (rem >> 4)];
        const f32x4 lv = lmv[rem];
        const f32x4 xv = xv4[(b << 4) | (rem & 15u)];
        f32x4 o;
        o.x = h * (xv.x - lv.x);
        o.y = h * (xv.y - lv.y);
        o.z = h * (xv.z - lv.z);
        o.w = h * (xv.w - lv.w);
        out[g4] = o;
    }
}

extern "C" void kernel_launch(void* const* d_in, const int* in_sizes, int n_in,
                              void* d_out, int out_size, void* d_ws, size_t ws_size,
                              hipStream_t stream) {
    const float* x  = (const float*)d_in[0];
    const float* lm = (const float*)d_in[1];
    const float* qd = (const float*)d_in[2];
    float* out = (float*)d_out;
    int* midx = (int*)d_ws;

    som_bmu_kernel<<<B_SZ / 8, 256, 0, stream>>>(x, lm, midx);

    som_delta_kernel<<<2048, 256, 0, stream>>>(x, lm, qd, midx, (f32x4*)out);
}

// Round 6
// 289.440 us; speedup vs baseline: 1.1952x; 1.1952x over previous
//
#include <hip/hip_runtime.h>

#define L_LM 2000
#define F_DIM 64
#define B_SZ 2048

typedef float f32x4 __attribute__((ext_vector_type(4)));

// ---------------- Kernel 1: BMU (argmin of squared distance) ----------------
// Unchanged from R3 (works, ~6-8 us).
__global__ __launch_bounds__(256) void som_bmu_kernel(
    const float* __restrict__ x, const float* __restrict__ lm,
    int* __restrict__ min_idx)
{
    constexpr int ROWS = 8;
    const int b0 = blockIdx.x * ROWS;
    const int tid = threadIdx.x;

    __shared__ float xs[ROWS][F_DIM];
    for (int i = tid; i < ROWS * F_DIM; i += 256) {
        xs[i / F_DIM][i % F_DIM] = x[(size_t)(b0 + i / F_DIM) * F_DIM + (i % F_DIM)];
    }
    __syncthreads();

    float best[ROWS];
    int   bidx[ROWS];
#pragma unroll
    for (int r = 0; r < ROWS; ++r) { best[r] = 3.4e38f; bidx[r] = 0; }

    for (int l = tid; l < L_LM; l += 256) {
        const float4* lp = reinterpret_cast<const float4*>(lm + (size_t)l * F_DIM);
        float dot[ROWS];
        float l2 = 0.f;
#pragma unroll
        for (int r = 0; r < ROWS; ++r) dot[r] = 0.f;
#pragma unroll
        for (int k = 0; k < F_DIM / 4; ++k) {
            float4 v = lp[k];
            l2 += v.x * v.x + v.y * v.y + v.z * v.z + v.w * v.w;
#pragma unroll
            for (int r = 0; r < ROWS; ++r) {
                dot[r] += v.x * xs[r][4 * k + 0] + v.y * xs[r][4 * k + 1]
                        + v.z * xs[r][4 * k + 2] + v.w * xs[r][4 * k + 3];
            }
        }
#pragma unroll
        for (int r = 0; r < ROWS; ++r) {
            float s = l2 - 2.f * dot[r];
            if (s < best[r]) { best[r] = s; bidx[r] = l; }  // per-thread l ascending
        }
    }

#pragma unroll
    for (int r = 0; r < ROWS; ++r) {
        float s = best[r]; int i = bidx[r];
        for (int off = 32; off > 0; off >>= 1) {
            float s2 = __shfl_down(s, off);
            int   i2 = __shfl_down(i, off);
            if (s2 < s || (s2 == s && i2 < i)) { s = s2; i = i2; }
        }
        best[r] = s; bidx[r] = i;
    }

    __shared__ float sbest[4][ROWS];
    __shared__ int   sidx[4][ROWS];
    const int wave = tid >> 6;
    const int lane = tid & 63;
    if (lane == 0) {
#pragma unroll
        for (int r = 0; r < ROWS; ++r) { sbest[wave][r] = best[r]; sidx[wave][r] = bidx[r]; }
    }
    __syncthreads();
    if (tid < ROWS) {
        float s = sbest[0][tid]; int i = sidx[0][tid];
#pragma unroll
        for (int w = 1; w < 4; ++w) {
            float s2 = sbest[w][tid]; int i2 = sidx[w][tid];
            if (s2 < s || (s2 == s && i2 < i)) { s = s2; i = i2; }
        }
        min_idx[b0 + tid] = i;
    }
}

// ---------------- Kernel 1c: h precompute ----------------
// hs[b][l] = qd[min_idx[b]][l]. 16.4 MB, ~6 us. Removes the min_idx->qd
// dependent indirection (random qd rows) from the store-bound hot loop.
// Plain stores: hs is re-read by the delta kernel, want it cached.
__global__ __launch_bounds__(256) void som_h_kernel(
    const float* __restrict__ qd, const int* __restrict__ min_idx,
    f32x4* __restrict__ hs4)
{
    constexpr unsigned NH4 = (unsigned)B_SZ * (L_LM / 4);  // 1,024,000
    constexpr unsigned RH4 = L_LM / 4;                      // 500
    const f32x4* __restrict__ qd4 = reinterpret_cast<const f32x4*>(qd);
    const unsigned stride = gridDim.x * 256u;
    for (unsigned i = blockIdx.x * 256u + threadIdx.x; i < NH4; i += stride) {
        const unsigned b = i / RH4;            // const-divisor magic mul
        const unsigned c = i - b * RH4;
        const unsigned bmu = (unsigned)min_idx[b];
        hs4[i] = qd4[bmu * RH4 + c];           // qd row offset 8000 B, 16B-aligned
    }
}

// ---------------- Kernel 2: delta0 write — fill-clone + nt + light loads ---
// Theory under test: the 6.8 TB/s rocclr fill = single compact grid-stride
// sliding window + ~zero loads + streaming stores. R5 tested the pattern but
// confounded it (dropped nt, added dependent min_idx->qd loads). This round:
// same pattern, nt restored, loads reduced to hs[g4>>4] (linear broadcast,
// no div needed: (b*32000+rem)>>4 == b*2000+(rem>>4)), lm[rem] (512 KB,
// L2-hot), x (L1-hot). No indirection in the loop.
__global__ __launch_bounds__(256) void som_delta_kernel(
    const float* __restrict__ x, const float* __restrict__ lm,
    const float* __restrict__ hs, f32x4* __restrict__ out)
{
    constexpr unsigned N4   = (unsigned)B_SZ * L_LM * (F_DIM / 4);  // 65,536,000
    constexpr unsigned ROW4 = L_LM * (F_DIM / 4);                    // 32,000
    const unsigned stride = gridDim.x * 256u;
    const f32x4* __restrict__ lmv = reinterpret_cast<const f32x4*>(lm);
    const f32x4* __restrict__ xv4 = reinterpret_cast<const f32x4*>(x);

#pragma unroll 5
    for (unsigned g4 = blockIdx.x * 256u + threadIdx.x; g4 < N4; g4 += stride) {
        const unsigned b   = g4 / ROW4;        // const-divisor magic mul
        const unsigned rem = g4 - b * ROW4;    // l*16 + f4
        const float h  = hs[(size_t)(g4 >> 4)];
        const f32x4 lv = lmv[rem];
        const f32x4 xv = xv4[(b << 4) | (rem & 15u)];
        f32x4 o;
        o.x = h * (xv.x - lv.x);
        o.y = h * (xv.y - lv.y);
        o.z = h * (xv.z - lv.z);
        o.w = h * (xv.w - lv.w);
        __builtin_nontemporal_store(o, &out[g4]);
    }
}

extern "C" void kernel_launch(void* const* d_in, const int* in_sizes, int n_in,
                              void* d_out, int out_size, void* d_ws, size_t ws_size,
                              hipStream_t stream) {
    const float* x  = (const float*)d_in[0];
    const float* lm = (const float*)d_in[1];
    const float* qd = (const float*)d_in[2];
    float* out = (float*)d_out;

    // ws layout: [0, 8KB) min_idx ; [1MB, 1MB+16.4MB) hs
    int*   midx = (int*)d_ws;
    float* hs   = (float*)((char*)d_ws + (1u << 20));

    som_bmu_kernel<<<B_SZ / 8, 256, 0, stream>>>(x, lm, midx);
    som_h_kernel<<<1024, 256, 0, stream>>>(qd, midx, (f32x4*)hs);
    som_delta_kernel<<<2048, 256, 0, stream>>>(x, lm, hs, (f32x4*)out);
}

// Round 7
// 275.351 us; speedup vs baseline: 1.2563x; 1.0512x over previous
//
#include <hip/hip_runtime.h>

#define L_LM 2000
#define F_DIM 64
#define B_SZ 2048
#define SPAN_L 80                 // landmarks per span (20 KB contiguous out)
#define SPANS_PER_ROW 25          // 2000 / 80
#define SPAN_F4 (SPAN_L * F_DIM / 4)   // 1280 float4 per span
#define DELTA_GRID 2048
#define KSTEPS 25                 // 51200 spans / 2048 blocks

typedef float f32x4 __attribute__((ext_vector_type(4)));

// ---------------- Kernel 1: BMU (argmin of squared distance) ----------------
__global__ __launch_bounds__(256) void som_bmu_kernel(
    const float* __restrict__ x, const float* __restrict__ lm,
    int* __restrict__ min_idx)
{
    constexpr int ROWS = 8;
    const int b0 = blockIdx.x * ROWS;
    const int tid = threadIdx.x;

    __shared__ float xs[ROWS][F_DIM];
    for (int i = tid; i < ROWS * F_DIM; i += 256) {
        xs[i / F_DIM][i % F_DIM] = x[(size_t)(b0 + i / F_DIM) * F_DIM + (i % F_DIM)];
    }
    __syncthreads();

    float best[ROWS];
    int   bidx[ROWS];
#pragma unroll
    for (int r = 0; r < ROWS; ++r) { best[r] = 3.4e38f; bidx[r] = 0; }

    for (int l = tid; l < L_LM; l += 256) {
        const float4* lp = reinterpret_cast<const float4*>(lm + (size_t)l * F_DIM);
        float dot[ROWS];
        float l2 = 0.f;
#pragma unroll
        for (int r = 0; r < ROWS; ++r) dot[r] = 0.f;
#pragma unroll
        for (int k = 0; k < F_DIM / 4; ++k) {
            float4 v = lp[k];
            l2 += v.x * v.x + v.y * v.y + v.z * v.z + v.w * v.w;
#pragma unroll
            for (int r = 0; r < ROWS; ++r) {
                dot[r] += v.x * xs[r][4 * k + 0] + v.y * xs[r][4 * k + 1]
                        + v.z * xs[r][4 * k + 2] + v.w * xs[r][4 * k + 3];
            }
        }
#pragma unroll
        for (int r = 0; r < ROWS; ++r) {
            float s = l2 - 2.f * dot[r];
            if (s < best[r]) { best[r] = s; bidx[r] = l; }
        }
    }

#pragma unroll
    for (int r = 0; r < ROWS; ++r) {
        float s = best[r]; int i = bidx[r];
        for (int off = 32; off > 0; off >>= 1) {
            float s2 = __shfl_down(s, off);
            int   i2 = __shfl_down(i, off);
            if (s2 < s || (s2 == s && i2 < i)) { s = s2; i = i2; }
        }
        best[r] = s; bidx[r] = i;
    }

    __shared__ float sbest[4][ROWS];
    __shared__ int   sidx[4][ROWS];
    const int wave = tid >> 6;
    const int lane = tid & 63;
    if (lane == 0) {
#pragma unroll
        for (int r = 0; r < ROWS; ++r) { sbest[wave][r] = best[r]; sidx[wave][r] = bidx[r]; }
    }
    __syncthreads();
    if (tid < ROWS) {
        float s = sbest[0][tid]; int i = sidx[0][tid];
#pragma unroll
        for (int w = 1; w < 4; ++w) {
            float s2 = sbest[w][tid]; int i2 = sidx[w][tid];
            if (s2 < s || (s2 == s && i2 < i)) { s = s2; i = i2; }
        }
        min_idx[b0 + tid] = i;
    }
}

// ---------------- Kernel 1c: h precompute (hs[b][l] = qd[min_idx[b]][l]) ---
__global__ __launch_bounds__(256) void som_h_kernel(
    const float* __restrict__ qd, const int* __restrict__ min_idx,
    f32x4* __restrict__ hs4)
{
    constexpr unsigned NH4 = (unsigned)B_SZ * (L_LM / 4);
    constexpr unsigned RH4 = L_LM / 4;
    const f32x4* __restrict__ qd4 = reinterpret_cast<const f32x4*>(qd);
    const unsigned stride = gridDim.x * 256u;
    for (unsigned i = blockIdx.x * 256u + threadIdx.x; i < NH4; i += stride) {
        const unsigned b = i / RH4;
        const unsigned c = i - b * RH4;
        hs4[i] = qd4[(unsigned)min_idx[b] * RH4 + c];
    }
}

// ---------------- Kernel 2: delta0 — compact writes + vmcnt-clean loop -----
// Deconfounded cell: R3's winner-trait (no global loads in the store loop ->
// no vmcnt waits gating store issue) COMBINED with fill-like compact linear
// write pattern. Block processes one 80-landmark span of one batch row
// (20 KB contiguous out). lm slice + h slice staged in LDS behind a barrier;
// store loop is LDS + VALU + nt stores only. 21 KB LDS -> 7 blocks/CU, so
// neighbors' store loops hide staging. Grid-strided spans (k*2048+bid) give
// a compact ~40 MB sliding global write window.
__global__ __launch_bounds__(256) void som_delta_kernel(
    const float* __restrict__ x, const float* __restrict__ lm,
    const float* __restrict__ hs, f32x4* __restrict__ out)
{
    __shared__ float lms[SPAN_L * F_DIM];   // 20.48 KB
    __shared__ float hls[SPAN_L];           // 320 B
    const int t = threadIdx.x;
    f32x4* lms4 = reinterpret_cast<f32x4*>(lms);
    const f32x4* __restrict__ lm4 = reinterpret_cast<const f32x4*>(lm);
    const f32x4* __restrict__ x4  = reinterpret_cast<const f32x4*>(x);

    for (int k = 0; k < KSTEPS; ++k) {
        const unsigned s  = (unsigned)k * DELTA_GRID + blockIdx.x;  // span id
        const unsigned b  = s / SPANS_PER_ROW;                      // magic mul
        const unsigned sr = s - b * SPANS_PER_ROW;

        // ---- stage (the only global loads; fenced off by the barrier) ----
#pragma unroll
        for (int j = 0; j < 5; ++j)
            lms4[j * 256 + t] = lm4[sr * SPAN_F4 + j * 256 + t];
        if (t < SPAN_L) hls[t] = hs[b * (unsigned)L_LM + sr * SPAN_L + t];
        const f32x4 xv = x4[(b << 4) | (t & 15u)];
        __syncthreads();

        // ---- store loop: LDS + VALU + nt stores only (vmcnt-clean) ----
        f32x4* __restrict__ ob = out + (size_t)s * SPAN_F4;
#pragma unroll
        for (int j = 0; j < 5; ++j) {
            const int idx = j * 256 + t;
            const float h  = hls[idx >> 4];
            const f32x4 lv = lms4[idx];
            f32x4 o;
            o.x = h * (xv.x - lv.x);
            o.y = h * (xv.y - lv.y);
            o.z = h * (xv.z - lv.z);
            o.w = h * (xv.w - lv.w);
            __builtin_nontemporal_store(o, &ob[idx]);
        }
        __syncthreads();   // LDS reused next k
    }
}

extern "C" void kernel_launch(void* const* d_in, const int* in_sizes, int n_in,
                              void* d_out, int out_size, void* d_ws, size_t ws_size,
                              hipStream_t stream) {
    const float* x  = (const float*)d_in[0];
    const float* lm = (const float*)d_in[1];
    const float* qd = (const float*)d_in[2];
    float* out = (float*)d_out;

    int*   midx = (int*)d_ws;
    float* hs   = (float*)((char*)d_ws + (1u << 20));

    som_bmu_kernel<<<B_SZ / 8, 256, 0, stream>>>(x, lm, midx);
    som_h_kernel<<<1024, 256, 0, stream>>>(qd, midx, (f32x4*)hs);
    som_delta_kernel<<<DELTA_GRID, 256, 0, stream>>>(x, lm, hs, (f32x4*)out);
}